// Round 11
// baseline (351.078 us; speedup 1.0000x reference)
//
#include <hip/hip_runtime.h>

// TemporalAttention, algebraically folded + MFMA everywhere it pays.
//   A-phase: QT[B,896] = q[B,288(pad)] @ Mmat[288,896]   (bf16 MFMA, cast fused)
//   B-phase: attention; block = 1 row; kv staged f32 to LDS (gload_lds, bulk);
//            QK^T via MFMA split across ALL 4 waves (partial-K accumulators
//            summed through LDS); uniform-scalar 2-pass softmax; PV in VALU.
//   C-phase: X[B,272] = VT[B,896] @ Pmat[896,272] + bias + residual + LN
// Column layout jj' = h*448 + j (j<444 valid, 444..447 pad, per head h).

namespace {
constexpr int kB = 16384;
constexpr int kN = 20;
constexpr float kScale = 0.08574929257125441f;  // 1/sqrt(136)
constexpr float kLnEps = 1e-5f;

// ws byte offsets
constexpr size_t kOffMsw = 0;                         // ushort[56*9*64*8]
constexpr size_t kOffPsw = kOffMsw + 516096;          // ushort[17*28*64*8]
constexpr size_t kOffQT16 = kOffPsw + 487424;         // ushort[16384*896]
}  // namespace

typedef __attribute__((ext_vector_type(8))) short s8v;
typedef __attribute__((ext_vector_type(4))) float f4v;

__device__ __forceinline__ unsigned short f2bf(float x) {
  unsigned int u = __float_as_uint(x);
  unsigned int r = (u + 0x7FFFu + ((u >> 16) & 1u)) >> 16;
  return (unsigned short)r;
}
__device__ __forceinline__ float bf2f(unsigned short h) {
  return __uint_as_float(((unsigned int)h) << 16);
}
// async global->LDS, 16B per lane; lds dest wave-uniform base (+lane*16 by HW)
__device__ __forceinline__ void gload16(const float4* g, float4* l) {
  __builtin_amdgcn_global_load_lds(
      (const __attribute__((address_space(1))) void*)g,
      (__attribute__((address_space(3))) void*)l, 16, 0, 0);
}
__device__ __forceinline__ float rfl(float x) {
  return __int_as_float(__builtin_amdgcn_readfirstlane(__float_as_int(x)));
}
__device__ __forceinline__ s8v pack8(float4 lo, float4 hi) {
  s8v a;
  a[0] = (short)f2bf(lo.x); a[1] = (short)f2bf(lo.y);
  a[2] = (short)f2bf(lo.z); a[3] = (short)f2bf(lo.w);
  a[4] = (short)f2bf(hi.x); a[5] = (short)f2bf(hi.y);
  a[6] = (short)f2bf(hi.z); a[7] = (short)f2bf(hi.w);
  return a;
}

// Msw[tile 0..55][ks 0..8][lane][e 0..7]: B-frag order for GEMM-A.
__global__ __launch_bounds__(64) void k_build_msw(const float* __restrict__ WQ,
                                                  const float* __restrict__ WK,
                                                  unsigned short* __restrict__ Msw) {
  const int e = blockIdx.x % 8;
  const int ks = (blockIdx.x / 8) % 9;
  const int tile = blockIdx.x / 72;
  const int l = threadIdx.x;
  const int jj = tile * 16 + (l & 15);
  const int h = jj / 448;
  const int j = jj - h * 448;
  const int i = ks * 32 + (l >> 4) * 8 + e;
  float s = 0.f;
  if (j < 444 && i < 272) {
    const float* wq = WQ + h * 136 * 272 + i;
    const float* wk = WK + h * 136 * 444 + j;
#pragma unroll 8
    for (int d = 0; d < 136; ++d) s = fmaf(wq[d * 272], wk[d * 444], s);
  }
  Msw[((size_t)(tile * 9 + ks) * 64 + l) * 8 + e] = f2bf(s);
}

// Psw[tile 0..16][ks 0..27][lane][e]: B-frag order for GEMM-C.
__global__ __launch_bounds__(64) void k_build_psw(const float* __restrict__ WO,
                                                  const float* __restrict__ WV,
                                                  unsigned short* __restrict__ Psw) {
  const int e = blockIdx.x % 8;
  const int ks = (blockIdx.x / 8) % 28;
  const int tile = blockIdx.x / 224;
  const int l = threadIdx.x;
  const int n = tile * 16 + (l & 15);
  const int k = ks * 32 + (l >> 4) * 8 + e;
  const int h = k / 448;
  const int j = k - h * 448;
  float s = 0.f;
  if (j < 444) {
    const float* wo = WO + (size_t)n * 272 + h * 136;
    const float* wv = WV + h * 136 * 444 + j;
#pragma unroll 8
    for (int d = 0; d < 136; ++d) s = fmaf(wo[d], wv[d * 444], s);
  }
  Psw[((size_t)(tile * 28 + ks) * 64 + l) * 8 + e] = f2bf(s);
}

// GEMM-A (cast fused): QT16[16 rows/block][896] = bf16(q) @ Mmat.
__global__ __launch_bounds__(256) void k_gemm_a(const float* __restrict__ node,
                                                const float* __restrict__ timef,
                                                const unsigned short* __restrict__ Msw,
                                                unsigned short* __restrict__ QT16) {
  const int tid = threadIdx.x;
  const int l = tid & 63, w = tid >> 6;
  const int m0 = blockIdx.x * 16;
  const int mrow = m0 + (l & 15);
  const int koff = (l >> 4) * 8;
  const float4* n4 = reinterpret_cast<const float4*>(node + (size_t)mrow * 172);
  const float4* t4 = reinterpret_cast<const float4*>(timef + (size_t)mrow * 100);
  const float4 z4 = make_float4(0.f, 0.f, 0.f, 0.f);
  f4v acc[14];
#pragma unroll
  for (int t = 0; t < 14; ++t) acc[t] = (f4v){0.f, 0.f, 0.f, 0.f};
  for (int ks = 0; ks < 9; ++ks) {
    const int c0 = ks * 32 + koff;
    float4 lo = z4, hi = z4;
    if (c0 + 8 <= 172) {
      lo = n4[c0 / 4];
      hi = n4[c0 / 4 + 1];
    } else if (c0 == 168) {
      lo = n4[42];
      hi = t4[0];
    } else if (c0 + 8 <= 272) {
      lo = t4[(c0 - 172) / 4];
      hi = t4[(c0 - 172) / 4 + 1];
    }
    const s8v a = pack8(lo, hi);
    const unsigned short* bp = Msw + ((size_t)(w * 14) * 9 + ks) * 64 * 8 + (size_t)l * 8;
#pragma unroll
    for (int t = 0; t < 14; ++t) {
      const s8v b = *reinterpret_cast<const s8v*>(bp + (size_t)t * 9 * 64 * 8);
      acc[t] = __builtin_amdgcn_mfma_f32_16x16x32_bf16(a, b, acc[t], 0, 0, 0);
    }
  }
  const int r0 = (l >> 4) * 4;
#pragma unroll
  for (int t = 0; t < 14; ++t) {
    const int n = (w * 14 + t) * 16 + (l & 15);
#pragma unroll
    for (int r = 0; r < 4; ++r)
      QT16[(size_t)(m0 + r0 + r) * 896 + n] = f2bf(acc[t][r]);
  }
}

// Phase B v8: one block (256 thr) per row; QK^T MFMA split over 4 waves.
__global__ __launch_bounds__(256) void k_attn(const float* __restrict__ nnode,
                                              const float* __restrict__ nedge,
                                              const float* __restrict__ ntime,
                                              const int* __restrict__ mask,
                                              unsigned short* __restrict__ QT16) {
  __shared__ float4 kvbuf[2220];   // f32 kv, [n][111 float4] (stride 444 f32)
  __shared__ float scrp[4][40];    // per-wave partial scores
  const int t = threadIdx.x;
  const int l = t & 63, w = t >> 6;
  const int b = blockIdx.x;
  const float4 z4 = make_float4(0.f, 0.f, 0.f, 0.f);
  const float4* nn = reinterpret_cast<const float4*>(nnode) + (size_t)b * kN * 43;
  const float4* ne = reinterpret_cast<const float4*>(nedge) + (size_t)b * kN * 43;
  const float4* nt = reinterpret_cast<const float4*>(ntime) + (size_t)b * kN * 25;
  unsigned short* qrow = QT16 + (size_t)b * 896;

  // ---- stage all 2220 float4 slots: slot s -> n=s/111, j4=s%111
#pragma unroll
  for (int r = 0; r < 9; ++r) {
    const int s = t + 256 * r;
    if (r < 8 || s < 2220) {
      const int n = s / 111;
      const int j4 = s - n * 111;
      const float4* src = (j4 < 43) ? nn + n * 43 + j4
                        : (j4 < 86) ? ne + n * 43 + (j4 - 43)
                                    : nt + n * 25 + (j4 - 86);
      gload16(src, &kvbuf[w * 64 + 256 * r]);
    }
  }
  __syncthreads();  // drains vmcnt: kv resident in LDS

  const float* kvf = reinterpret_cast<const float*>(kvbuf);

  // ---- QK^T via MFMA, all 4 waves: wave w owns ks in [4w, min(4w+4,14)).
  // A = Q~ rows {head0, head1, dup...}; B cols = neighbors (tile1: 0-15,
  // tile2: 16-19 valid). Partial-K accumulators summed via LDS.
  {
    f4v acc1 = (f4v){0.f, 0.f, 0.f, 0.f};
    f4v acc2 = (f4v){0.f, 0.f, 0.f, 0.f};
    const int c = l & 15;
    const int hh = (c < 2) ? c : 1;
    const int koff = (l >> 4) * 8;
    const int n2raw = 16 + c;
    const int n2 = (n2raw < kN) ? n2raw : 0;  // clamp (garbage col, unread)
    const int ks0 = w * 4;
    const int ks1 = (ks0 + 4 < 14) ? ks0 + 4 : 14;
    for (int ks = ks0; ks < ks1; ++ks) {
      const int j0 = ks * 32 + koff;
      const s8v a = *reinterpret_cast<const s8v*>(qrow + hh * 448 + j0);
      const float4 b1lo = *reinterpret_cast<const float4*>(kvf + c * 444 + j0);
      const float4 b1hi = (j0 + 8 <= 444)
          ? *reinterpret_cast<const float4*>(kvf + c * 444 + j0 + 4) : z4;
      const float4 b2lo = *reinterpret_cast<const float4*>(kvf + n2 * 444 + j0);
      const float4 b2hi = (j0 + 8 <= 444)
          ? *reinterpret_cast<const float4*>(kvf + n2 * 444 + j0 + 4) : z4;
      acc1 = __builtin_amdgcn_mfma_f32_16x16x32_bf16(a, pack8(b1lo, b1hi), acc1, 0, 0, 0);
      acc2 = __builtin_amdgcn_mfma_f32_16x16x32_bf16(a, pack8(b2lo, b2hi), acc2, 0, 0, 0);
    }
    // D: col = l&15 (neighbor), row = (l>>4)*4 + reg. Lanes 0-15: reg0=head0,
    // reg1=head1.
    if ((l >> 4) == 0) {
      scrp[w][c] = acc1[0];
      scrp[w][20 + c] = acc1[1];
      if (c < 4) {
        scrp[w][16 + c] = acc2[0];
        scrp[w][36 + c] = acc2[1];
      }
    }
  }
  __syncthreads();

  // ---- every thread: sum partials, uniform two-pass softmax
  float sc[40];
#pragma unroll
  for (int i = 0; i < 40; ++i)
    sc[i] = (scrp[0][i] + scrp[1][i]) + (scrp[2][i] + scrp[3][i]);
  const int* mrow = mask + (size_t)b * kN;
  float s0[kN], s1[kN];
  float M0 = -1e30f, M1 = -1e30f;
#pragma unroll
  for (int n = 0; n < kN; ++n) {
    const bool mz = (mrow[n] == 0);
    s0[n] = mz ? -1e10f : sc[n] * kScale;
    s1[n] = mz ? -1e10f : sc[20 + n] * kScale;
    M0 = fmaxf(M0, s0[n]);
    M1 = fmaxf(M1, s1[n]);
  }
  float L0 = 0.f, L1 = 0.f;
  float p0[kN], p1[kN];
#pragma unroll
  for (int n = 0; n < kN; ++n) {
    p0[n] = __expf(s0[n] - M0);
    p1[n] = __expf(s1[n] - M1);
    L0 += p0[n];
    L1 += p1[n];
  }
  const float i0 = rfl(1.0f / L0);
  const float i1 = rfl(1.0f / L1);

  // ---- PV: thread t < 222 owns float2 slice j = {2t, 2t+1}
  if (t < 222) {
    float o00 = 0.f, o01 = 0.f, o10 = 0.f, o11 = 0.f;
#pragma unroll
    for (int n = 0; n < kN; ++n) {
      const float2 v = *reinterpret_cast<const float2*>(kvf + n * 444 + 2 * t);
      o00 = fmaf(p0[n], v.x, o00);
      o01 = fmaf(p0[n], v.y, o01);
      o10 = fmaf(p1[n], v.x, o10);
      o11 = fmaf(p1[n], v.y, o11);
    }
    const unsigned int w0 = (unsigned int)f2bf(o00 * i0) | ((unsigned int)f2bf(o01 * i0) << 16);
    const unsigned int w1 = (unsigned int)f2bf(o10 * i1) | ((unsigned int)f2bf(o11 * i1) << 16);
    *reinterpret_cast<unsigned int*>(qrow + 2 * t) = w0;
    *reinterpret_cast<unsigned int*>(qrow + 448 + 2 * t) = w1;
  }
}

// GEMM-C + bias + residual + LayerNorm. 4 waves; wave w owns n-tiles w,w+4,...
__global__ __launch_bounds__(256) void k_out_mfma(const unsigned short* __restrict__ VT16,
                                                  const unsigned short* __restrict__ Psw,
                                                  const float* __restrict__ node,
                                                  const float* __restrict__ timef,
                                                  const float* __restrict__ bO,
                                                  const float* __restrict__ g,
                                                  const float* __restrict__ be,
                                                  float* __restrict__ out) {
  __shared__ float xl[16][273];
  const int tid = threadIdx.x;
  const int l = tid & 63, w = tid >> 6;
  const int m0 = blockIdx.x * 16;
  const int mrow = m0 + (l & 15);
  const int koff = (l >> 4) * 8;
  f4v acc[5];
#pragma unroll
  for (int i = 0; i < 5; ++i) acc[i] = (f4v){0.f, 0.f, 0.f, 0.f};
  for (int ks = 0; ks < 28; ++ks) {
    const s8v a = *reinterpret_cast<const s8v*>(VT16 + (size_t)mrow * 896 + ks * 32 + koff);
#pragma unroll
    for (int i = 0; i < 5; ++i) {
      const int t = w + 4 * i;
      if (t < 17) {
        const s8v bfr = *reinterpret_cast<const s8v*>(Psw + ((size_t)(t * 28 + ks) * 64 + l) * 8);
        acc[i] = __builtin_amdgcn_mfma_f32_16x16x32_bf16(a, bfr, acc[i], 0, 0, 0);
      }
    }
  }
  const int r0 = (l >> 4) * 4;
#pragma unroll
  for (int i = 0; i < 5; ++i) {
    const int t = w + 4 * i;
    if (t < 17) {
#pragma unroll
      for (int r = 0; r < 4; ++r) xl[r0 + r][t * 16 + (l & 15)] = acc[i][r];
    }
  }
  __syncthreads();
  for (int bb = w; bb < 16; bb += 4) {
    const int b = m0 + bb;
    float v[5];
    float sum = 0.f, sq = 0.f;
#pragma unroll
    for (int k = 0; k < 5; ++k) {
      const int o = l + 64 * k;
      v[k] = 0.f;
      if (o < 272) {
        const float r = (o < 172) ? node[(size_t)b * 172 + o] : timef[(size_t)b * 100 + (o - 172)];
        const float x = xl[bb][o] + bO[o] + r;
        v[k] = x;
        sum += x;
        sq = fmaf(x, x, sq);
      }
    }
#pragma unroll
    for (int off = 32; off >= 1; off >>= 1) {
      sum += __shfl_xor(sum, off, 64);
      sq += __shfl_xor(sq, off, 64);
    }
    const float mu = sum * (1.0f / 272.0f);
    const float var = sq * (1.0f / 272.0f) - mu * mu;
    const float rs = rsqrtf(var + kLnEps);
#pragma unroll
    for (int k = 0; k < 5; ++k) {
      const int o = l + 64 * k;
      if (o < 272) out[(size_t)b * 272 + o] = (v[k] - mu) * rs * g[o] + be[o];
    }
  }
}

extern "C" void kernel_launch(void* const* d_in, const int* in_sizes, int n_in,
                              void* d_out, int out_size, void* d_ws, size_t ws_size,
                              hipStream_t stream) {
  const float* node = (const float*)d_in[0];
  const float* timef = (const float*)d_in[1];
  const float* nnode = (const float*)d_in[2];
  const float* ntime = (const float*)d_in[3];
  const float* nedge = (const float*)d_in[4];
  const int* mask = (const int*)d_in[5];
  const float* WQ = (const float*)d_in[6];
  const float* WK = (const float*)d_in[7];
  const float* WV = (const float*)d_in[8];
  const float* WO = (const float*)d_in[9];
  const float* bO = (const float*)d_in[10];
  const float* g = (const float*)d_in[11];
  const float* be = (const float*)d_in[12];

  char* ws = (char*)d_ws;
  unsigned short* Msw = (unsigned short*)(ws + kOffMsw);
  unsigned short* Psw = (unsigned short*)(ws + kOffPsw);
  unsigned short* QT16 = (unsigned short*)(ws + kOffQT16);
  float* out = (float*)d_out;

  hipLaunchKernelGGL(k_build_msw, dim3(56 * 9 * 8), dim3(64), 0, stream, WQ, WK, Msw);
  hipLaunchKernelGGL(k_build_psw, dim3(17 * 28 * 8), dim3(64), 0, stream, WO, WV, Psw);
  hipLaunchKernelGGL(k_gemm_a, dim3(kB / 16), dim3(256), 0, stream, node, timef, Msw, QT16);
  hipLaunchKernelGGL(k_attn, dim3(kB), dim3(256), 0, stream, nnode, nedge, ntime, mask, QT16);
  hipLaunchKernelGGL(k_out_mfma, dim3(kB / 16), dim3(256), 0, stream, QT16, Psw, node, timef, bO, g, be, out);
}

// Round 12
// 249.673 us; speedup vs baseline: 1.4061x; 1.4061x over previous
//
#include <hip/hip_runtime.h>

// TemporalAttention, algebraically folded + MFMA for the two matvec phases.
//   A-phase: QT[B,896] = q[B,288(pad)] @ Mmat[288,896]   (bf16 MFMA, cast fused)
//   B-phase: attention; wave = 1 row, online softmax, kv read once (r1 kernel,
//            best-measured of 11 variants: 174 us).
//   C-phase: X[B,272] = VT[B,896] @ Pmat[896,272] + bias + residual + LN
// Column layout jj' = h*448 + j (j<444 valid, 444..447 pad, per head h).

namespace {
constexpr int kB = 16384;
constexpr int kN = 20;
constexpr float kScale = 0.08574929257125441f;  // 1/sqrt(136)
constexpr float kLnEps = 1e-5f;

// ws byte offsets
constexpr size_t kOffMsw = 0;                         // ushort[56*9*64*8]
constexpr size_t kOffPsw = kOffMsw + 516096;          // ushort[17*28*64*8]
constexpr size_t kOffQT16 = kOffPsw + 487424;         // ushort[16384*896]

constexpr int kMswBlocks = 56 * 9 * 8;                // 4032
constexpr int kPswBlocks = 17 * 28 * 8;               // 3808
}  // namespace

typedef __attribute__((ext_vector_type(8))) short s8v;
typedef __attribute__((ext_vector_type(4))) float f4v;

__device__ __forceinline__ unsigned short f2bf(float x) {
  unsigned int u = __float_as_uint(x);
  unsigned int r = (u + 0x7FFFu + ((u >> 16) & 1u)) >> 16;
  return (unsigned short)r;
}
__device__ __forceinline__ float bf2f(unsigned short h) {
  return __uint_as_float(((unsigned int)h) << 16);
}
__device__ __forceinline__ float fma4(float4 a, float4 b, float acc) {
  acc = fmaf(a.x, b.x, acc);
  acc = fmaf(a.y, b.y, acc);
  acc = fmaf(a.z, b.z, acc);
  acc = fmaf(a.w, b.w, acc);
  return acc;
}
__device__ __forceinline__ s8v pack8(float4 lo, float4 hi) {
  s8v a;
  a[0] = (short)f2bf(lo.x); a[1] = (short)f2bf(lo.y);
  a[2] = (short)f2bf(lo.z); a[3] = (short)f2bf(lo.w);
  a[4] = (short)f2bf(hi.x); a[5] = (short)f2bf(hi.y);
  a[6] = (short)f2bf(hi.z); a[7] = (short)f2bf(hi.w);
  return a;
}

// Merged weight-fold: blocks [0, kMswBlocks) build Msw, rest build Psw.
// Msw[tile 0..55][ks 0..8][lane][e]: Mmat[i][jj] = sum_d WQ[.][i]*WK[.][j]
// Psw[tile 0..16][ks 0..27][lane][e]: Pmat[k][n] = sum_d WO[n][.]*WV[.][j]
__global__ __launch_bounds__(64) void k_build_mp(const float* __restrict__ WQ,
                                                 const float* __restrict__ WK,
                                                 const float* __restrict__ WO,
                                                 const float* __restrict__ WV,
                                                 unsigned short* __restrict__ Msw,
                                                 unsigned short* __restrict__ Psw) {
  const int l = threadIdx.x;
  if (blockIdx.x < kMswBlocks) {
    const int bid = blockIdx.x;
    const int e = bid % 8;
    const int ks = (bid / 8) % 9;
    const int tile = bid / 72;
    const int jj = tile * 16 + (l & 15);
    const int h = jj / 448;
    const int j = jj - h * 448;
    const int i = ks * 32 + (l >> 4) * 8 + e;
    float s = 0.f;
    if (j < 444 && i < 272) {
      const float* wq = WQ + h * 136 * 272 + i;
      const float* wk = WK + h * 136 * 444 + j;
#pragma unroll 8
      for (int d = 0; d < 136; ++d) s = fmaf(wq[d * 272], wk[d * 444], s);
    }
    Msw[((size_t)(tile * 9 + ks) * 64 + l) * 8 + e] = f2bf(s);
  } else {
    const int bid = blockIdx.x - kMswBlocks;
    const int e = bid % 8;
    const int ks = (bid / 8) % 28;
    const int tile = bid / 224;
    const int n = tile * 16 + (l & 15);
    const int k = ks * 32 + (l >> 4) * 8 + e;
    const int h = k / 448;
    const int j = k - h * 448;
    float s = 0.f;
    if (j < 444) {
      const float* wo = WO + (size_t)n * 272 + h * 136;
      const float* wv = WV + h * 136 * 444 + j;
#pragma unroll 8
      for (int d = 0; d < 136; ++d) s = fmaf(wo[d], wv[d * 444], s);
    }
    Psw[((size_t)(tile * 28 + ks) * 64 + l) * 8 + e] = f2bf(s);
  }
}

// GEMM-A (cast fused): QT16[16 rows/block][896] = bf16(q) @ Mmat.
__global__ __launch_bounds__(256) void k_gemm_a(const float* __restrict__ node,
                                                const float* __restrict__ timef,
                                                const unsigned short* __restrict__ Msw,
                                                unsigned short* __restrict__ QT16) {
  const int tid = threadIdx.x;
  const int l = tid & 63, w = tid >> 6;
  const int m0 = blockIdx.x * 16;
  const int mrow = m0 + (l & 15);
  const int koff = (l >> 4) * 8;
  const float4* n4 = reinterpret_cast<const float4*>(node + (size_t)mrow * 172);
  const float4* t4 = reinterpret_cast<const float4*>(timef + (size_t)mrow * 100);
  const float4 z4 = make_float4(0.f, 0.f, 0.f, 0.f);
  f4v acc[14];
#pragma unroll
  for (int t = 0; t < 14; ++t) acc[t] = (f4v){0.f, 0.f, 0.f, 0.f};
  for (int ks = 0; ks < 9; ++ks) {
    const int c0 = ks * 32 + koff;
    float4 lo = z4, hi = z4;
    if (c0 + 8 <= 172) {
      lo = n4[c0 / 4];
      hi = n4[c0 / 4 + 1];
    } else if (c0 == 168) {
      lo = n4[42];
      hi = t4[0];
    } else if (c0 + 8 <= 272) {
      lo = t4[(c0 - 172) / 4];
      hi = t4[(c0 - 172) / 4 + 1];
    }
    const s8v a = pack8(lo, hi);
    const unsigned short* bp = Msw + ((size_t)(w * 14) * 9 + ks) * 64 * 8 + (size_t)l * 8;
#pragma unroll
    for (int t = 0; t < 14; ++t) {
      const s8v b = *reinterpret_cast<const s8v*>(bp + (size_t)t * 9 * 64 * 8);
      acc[t] = __builtin_amdgcn_mfma_f32_16x16x32_bf16(a, b, acc[t], 0, 0, 0);
    }
  }
  const int r0 = (l >> 4) * 4;
#pragma unroll
  for (int t = 0; t < 14; ++t) {
    const int n = (w * 14 + t) * 16 + (l & 15);
#pragma unroll
    for (int r = 0; r < 4; ++r)
      QT16[(size_t)(m0 + r0 + r) * 896 + n] = f2bf(acc[t][r]);
  }
}

// Phase B (round-1 kernel, best-measured): one wave per batch row; online
// softmax; kv read exactly once. Lane l holds float4 slots l and 64+l (l<47).
__global__ __launch_bounds__(256) void k_attn(const float* __restrict__ nnode,
                                              const float* __restrict__ nedge,
                                              const float* __restrict__ ntime,
                                              const int* __restrict__ mask,
                                              unsigned short* __restrict__ QT16) {
  const int l = threadIdx.x & 63;
  const int w = threadIdx.x >> 6;
  const int b = blockIdx.x * 4 + w;
  const bool v1 = (l < 47);
  const float4* nnode4 = reinterpret_cast<const float4*>(nnode);  // rows of 43
  const float4* nedge4 = reinterpret_cast<const float4*>(nedge);  // rows of 43
  const float4* ntime4 = reinterpret_cast<const float4*>(ntime);  // rows of 25
  const float4 z4 = make_float4(0.f, 0.f, 0.f, 0.f);
  unsigned short* qrow = QT16 + (size_t)b * 896;

  auto ldq = [&](int so) {
    const ushort4 u = *reinterpret_cast<const ushort4*>(qrow + so);
    return make_float4(bf2f(u.x), bf2f(u.y), bf2f(u.z), bf2f(u.w));
  };
  const float4 q00 = ldq(4 * l);
  const float4 q01 = v1 ? ldq(256 + 4 * l) : z4;
  const float4 q10 = ldq(448 + 4 * l);
  const float4 q11 = v1 ? ldq(448 + 256 + 4 * l) : z4;

  float4 va00 = z4, va01 = z4, va10 = z4, va11 = z4;
  float m0 = -1e30f, m1 = -1e30f, l0 = 0.f, l1 = 0.f;

  for (int n = 0; n < kN; ++n) {
    const size_t row = (size_t)b * kN + n;
    float4 kv0 = (l < 43) ? nnode4[row * 43 + l] : nedge4[row * 43 + (l - 43)];
    float4 kv1 = z4;
    if (v1) {
      const int j4 = 64 + l;
      kv1 = (j4 < 86) ? nedge4[row * 43 + (j4 - 43)] : ntime4[row * 25 + (j4 - 86)];
    }
    float ps0 = fma4(q01, kv1, fma4(q00, kv0, 0.f));
    float ps1 = fma4(q11, kv1, fma4(q10, kv0, 0.f));
#pragma unroll
    for (int off = 32; off >= 1; off >>= 1) {
      ps0 += __shfl_xor(ps0, off, 64);
      ps1 += __shfl_xor(ps1, off, 64);
    }
    const int mk = mask[row];
    const float s0 = (mk == 0) ? -1e10f : ps0 * kScale;
    const float s1 = (mk == 0) ? -1e10f : ps1 * kScale;
    {
      const float mn = fmaxf(m0, s0);
      const float al = __expf(m0 - mn);
      const float p = __expf(s0 - mn);
      l0 = l0 * al + p;
      m0 = mn;
      va00.x = fmaf(p, kv0.x, va00.x * al);
      va00.y = fmaf(p, kv0.y, va00.y * al);
      va00.z = fmaf(p, kv0.z, va00.z * al);
      va00.w = fmaf(p, kv0.w, va00.w * al);
      va01.x = fmaf(p, kv1.x, va01.x * al);
      va01.y = fmaf(p, kv1.y, va01.y * al);
      va01.z = fmaf(p, kv1.z, va01.z * al);
      va01.w = fmaf(p, kv1.w, va01.w * al);
    }
    {
      const float mn = fmaxf(m1, s1);
      const float al = __expf(m1 - mn);
      const float p = __expf(s1 - mn);
      l1 = l1 * al + p;
      m1 = mn;
      va10.x = fmaf(p, kv0.x, va10.x * al);
      va10.y = fmaf(p, kv0.y, va10.y * al);
      va10.z = fmaf(p, kv0.z, va10.z * al);
      va10.w = fmaf(p, kv0.w, va10.w * al);
      va11.x = fmaf(p, kv1.x, va11.x * al);
      va11.y = fmaf(p, kv1.y, va11.y * al);
      va11.z = fmaf(p, kv1.z, va11.z * al);
      va11.w = fmaf(p, kv1.w, va11.w * al);
    }
  }
  const float i0 = 1.0f / l0;
  const float i1 = 1.0f / l1;
  auto stq = [&](int so, float4 v, float s) {
    ushort4 u;
    u.x = f2bf(v.x * s); u.y = f2bf(v.y * s); u.z = f2bf(v.z * s); u.w = f2bf(v.w * s);
    *reinterpret_cast<ushort4*>(qrow + so) = u;
  };
  stq(4 * l, va00, i0);
  if (v1) stq(256 + 4 * l, va01, i0);
  stq(448 + 4 * l, va10, i1);
  if (v1) stq(448 + 256 + 4 * l, va11, i1);
}

// GEMM-C + bias + residual + LayerNorm. 4 waves; wave w owns n-tiles w,w+4,...
__global__ __launch_bounds__(256) void k_out_mfma(const unsigned short* __restrict__ VT16,
                                                  const unsigned short* __restrict__ Psw,
                                                  const float* __restrict__ node,
                                                  const float* __restrict__ timef,
                                                  const float* __restrict__ bO,
                                                  const float* __restrict__ g,
                                                  const float* __restrict__ be,
                                                  float* __restrict__ out) {
  __shared__ float xl[16][273];
  const int tid = threadIdx.x;
  const int l = tid & 63, w = tid >> 6;
  const int m0 = blockIdx.x * 16;
  const int mrow = m0 + (l & 15);
  const int koff = (l >> 4) * 8;
  f4v acc[5];
#pragma unroll
  for (int i = 0; i < 5; ++i) acc[i] = (f4v){0.f, 0.f, 0.f, 0.f};
  for (int ks = 0; ks < 28; ++ks) {
    const s8v a = *reinterpret_cast<const s8v*>(VT16 + (size_t)mrow * 896 + ks * 32 + koff);
#pragma unroll
    for (int i = 0; i < 5; ++i) {
      const int t = w + 4 * i;
      if (t < 17) {
        const s8v bfr = *reinterpret_cast<const s8v*>(Psw + ((size_t)(t * 28 + ks) * 64 + l) * 8);
        acc[i] = __builtin_amdgcn_mfma_f32_16x16x32_bf16(a, bfr, acc[i], 0, 0, 0);
      }
    }
  }
  const int r0 = (l >> 4) * 4;
#pragma unroll
  for (int i = 0; i < 5; ++i) {
    const int t = w + 4 * i;
    if (t < 17) {
#pragma unroll
      for (int r = 0; r < 4; ++r) xl[r0 + r][t * 16 + (l & 15)] = acc[i][r];
    }
  }
  __syncthreads();
  for (int bb = w; bb < 16; bb += 4) {
    const int b = m0 + bb;
    float v[5];
    float sum = 0.f, sq = 0.f;
#pragma unroll
    for (int k = 0; k < 5; ++k) {
      const int o = l + 64 * k;
      v[k] = 0.f;
      if (o < 272) {
        const float r = (o < 172) ? node[(size_t)b * 172 + o] : timef[(size_t)b * 100 + (o - 172)];
        const float x = xl[bb][o] + bO[o] + r;
        v[k] = x;
        sum += x;
        sq = fmaf(x, x, sq);
      }
    }
#pragma unroll
    for (int off = 32; off >= 1; off >>= 1) {
      sum += __shfl_xor(sum, off, 64);
      sq += __shfl_xor(sq, off, 64);
    }
    const float mu = sum * (1.0f / 272.0f);
    const float var = sq * (1.0f / 272.0f) - mu * mu;
    const float rs = rsqrtf(var + kLnEps);
#pragma unroll
    for (int k = 0; k < 5; ++k) {
      const int o = l + 64 * k;
      if (o < 272) out[(size_t)b * 272 + o] = (v[k] - mu) * rs * g[o] + be[o];
    }
  }
}

extern "C" void kernel_launch(void* const* d_in, const int* in_sizes, int n_in,
                              void* d_out, int out_size, void* d_ws, size_t ws_size,
                              hipStream_t stream) {
  const float* node = (const float*)d_in[0];
  const float* timef = (const float*)d_in[1];
  const float* nnode = (const float*)d_in[2];
  const float* ntime = (const float*)d_in[3];
  const float* nedge = (const float*)d_in[4];
  const int* mask = (const int*)d_in[5];
  const float* WQ = (const float*)d_in[6];
  const float* WK = (const float*)d_in[7];
  const float* WV = (const float*)d_in[8];
  const float* WO = (const float*)d_in[9];
  const float* bO = (const float*)d_in[10];
  const float* g = (const float*)d_in[11];
  const float* be = (const float*)d_in[12];

  char* ws = (char*)d_ws;
  unsigned short* Msw = (unsigned short*)(ws + kOffMsw);
  unsigned short* Psw = (unsigned short*)(ws + kOffPsw);
  unsigned short* QT16 = (unsigned short*)(ws + kOffQT16);
  float* out = (float*)d_out;

  hipLaunchKernelGGL(k_build_mp, dim3(kMswBlocks + kPswBlocks), dim3(64), 0, stream,
                     WQ, WK, WO, WV, Msw, Psw);
  hipLaunchKernelGGL(k_gemm_a, dim3(kB / 16), dim3(256), 0, stream, node, timef, Msw, QT16);
  hipLaunchKernelGGL(k_attn, dim3(kB / 4), dim3(256), 0, stream, nnode, nedge, ntime, mask, QT16);
  hipLaunchKernelGGL(k_out_mfma, dim3(kB / 16), dim3(256), 0, stream, QT16, Psw, node, timef, bO, g, be, out);
}